// Round 1
// baseline (9465.646 us; speedup 1.0000x reference)
//
#include <hip/hip_runtime.h>
#include <float.h>

#define V 50000
#define E 100
#define H 512
#define T 200
#define B 256
#define NC 5
#define K0 640            // layer0 concat-K: 128 (emb pad) + 512
#define K1 1024           // layer1 concat-K: 512 + 512
#define NH (B * H)        // 131072
#define NW0 (2048 * K0)
#define NW1 (2048 * K1)
#define LOSC 4096.0f      // lo-plane scale (2^12) keeps lo out of fp16 denormals
#define ILOSC (1.0f / 4096.0f)
#define NBLK 256          // persistent grid size (1 block / CU)

typedef _Float16 half8 __attribute__((ext_vector_type(8)));
typedef float floatx4 __attribute__((ext_vector_type(4)));

// ---------------- activations ----------------
__device__ __forceinline__ float fsig(float x)  { return 1.f / (1.f + __expf(-x)); }
__device__ __forceinline__ float ftanh(float x) { return 1.f - 2.f / (__expf(2.f * x) + 1.f); }

// ---------------- workspace map ----------------
struct WS {
    _Float16 *W0h, *W0l, *W1h, *W1l;   // [2048][K] split planes, c = j*4+g
    _Float16 *h0h, *h0l, *h1h, *h1l;   // [2 slots][B][H] split planes (lo pre-scaled)
    float *c0, *c1, *hmax;             // c0/c1 now unused (register-resident); hmax written once at end
    int *last;
    unsigned *bar;                     // grid barrier counter (monotonic per launch)
};
__device__ __host__ inline WS wsmap(char* p) {
    WS w;
    w.W0h = (_Float16*)p;  p += (size_t)NW0 * 2;
    w.W0l = (_Float16*)p;  p += (size_t)NW0 * 2;
    w.W1h = (_Float16*)p;  p += (size_t)NW1 * 2;
    w.W1l = (_Float16*)p;  p += (size_t)NW1 * 2;
    w.h0h = (_Float16*)p;  p += (size_t)2 * NH * 2;
    w.h0l = (_Float16*)p;  p += (size_t)2 * NH * 2;
    w.h1h = (_Float16*)p;  p += (size_t)2 * NH * 2;
    w.h1l = (_Float16*)p;  p += (size_t)2 * NH * 2;
    w.c0   = (float*)p;    p += (size_t)NH * 4;
    w.c1   = (float*)p;    p += (size_t)NH * 4;
    w.hmax = (float*)p;    p += (size_t)NH * 4;
    w.last = (int*)p;      p += (size_t)B * 4;
    w.bar  = (unsigned*)p;
    return w;
}

// ---------------- prep: split weights into fp16 hi/lo catenated layout ----------------
__global__ void k_prep(const float* __restrict__ Wih0, const float* __restrict__ Whh0,
                       const float* __restrict__ Wih1, const float* __restrict__ Whh1,
                       char* wsraw) {
    WS w = wsmap(wsraw);
    int idx = blockIdx.x * 256 + threadIdx.x;
    if (idx < NW0) {
        int c = idx / K0, k = idx - c * K0;
        int jx = c >> 2, g = c & 3, row = g * H + jx;
        float v = 0.f;
        if (k < 128) { if (k < E) v = Wih0[(size_t)row * E + k]; }
        else           v = Whh0[(size_t)row * H + (k - 128)];
        _Float16 hh = (_Float16)v;
        w.W0h[idx] = hh;
        w.W0l[idx] = (_Float16)((v - (float)hh) * LOSC);
    } else if (idx < NW0 + NW1) {
        int i2 = idx - NW0;
        int c = i2 / K1, k = i2 - c * K1;
        int jx = c >> 2, g = c & 3, row = g * H + jx;
        float v = (k < H) ? Wih1[(size_t)row * H + k]
                          : Whh1[(size_t)row * H + (k - H)];
        _Float16 hh = (_Float16)v;
        w.W1h[i2] = hh;
        w.W1l[i2] = (_Float16)((v - (float)hh) * LOSC);
    }
}

// ---------------- init: zero h planes, last[b], barrier counter ----------------
__global__ void k_init(const int* __restrict__ X, char* wsraw) {
    WS w = wsmap(wsraw);
    int i = blockIdx.x * 256 + threadIdx.x;
    if (i < 524288) ((unsigned*)w.h0h)[i] = 0u;   // h0h,h0l,h1h,h1l contiguous = 2 MiB
    if (i < B) {
        int l = -1;
        const int* xr = X + i * T;
        for (int t = 0; t < T; ++t) if (xr[t] != V) l = t;
        w.last[i] = l;
    }
    if (i == 0) *w.bar = 0u;
}

// ---------------- device-scope grid barrier (all NBLK blocks co-resident) ----------
__device__ __forceinline__ void grid_sync(unsigned* cnt, unsigned target) {
    __syncthreads();
    if (threadIdx.x == 0) {
        __threadfence();  // release: drain stores + L2 writeback (agent scope)
        __hip_atomic_fetch_add(cnt, 1u, __ATOMIC_RELAXED, __HIP_MEMORY_SCOPE_AGENT);
        while (__hip_atomic_load(cnt, __ATOMIC_RELAXED, __HIP_MEMORY_SCOPE_AGENT) < target)
            __builtin_amdgcn_s_sleep(1);
        __threadfence();  // acquire: L2 invalidate so cross-XCD h-writes are visible
    }
    __syncthreads();
}

// ---------------- K-quarter MFMA loop (per wave), all frags direct from global/L2 ----
template <int LAYER>
__device__ __forceinline__ void run_mm(
    int t, const int* __restrict__ X, const float* __restrict__ emb,
    const _Float16* __restrict__ Wh, const _Float16* __restrict__ Wl,
    const _Float16* __restrict__ xh0, const _Float16* __restrict__ xl0,
    const _Float16* __restrict__ xh1, const _Float16* __restrict__ xl1,
    int c0g, int b0gl, int m, int qq, int wq,
    floatx4 (&acc0)[16], floatx4 (&acc1)[16])
{
    const int KT  = LAYER ? K1 : K0;
    const int NKB = LAYER ? 8 : 5;    // k-blocks of 32 per wave (kb = wq + 4*i)
    int erow[4];
    if (LAYER == 0) {
#pragma unroll
        for (int bs = 0; bs < 4; ++bs)
            erow[bs] = X[(b0gl + bs * 16 + m) * T + t];
    }
    half8 A_h[2][4], A_l[2][4], B_h[2][4], B_l[2][4];

    auto ldkb = [&](int kb, int buf) {
        const int ko = kb * 32 + qq * 8;
#pragma unroll
        for (int cs = 0; cs < 4; ++cs) {
            const size_t ro = (size_t)(c0g + cs * 16 + m) * KT + ko;
            A_h[buf][cs] = *(const half8*)(Wh + ro);
            A_l[buf][cs] = *(const half8*)(Wl + ro);
        }
        if (LAYER == 0 && kb < 4) {            // embedding part, convert on the fly
#pragma unroll
            for (int bs = 0; bs < 4; ++bs) {
                const float* er = emb + (size_t)erow[bs] * E;
                float4 fa = make_float4(0.f,0.f,0.f,0.f), fb = fa;
                if (ko <= 96) fa = *(const float4*)(er + ko);
                if (ko <= 92) fb = *(const float4*)(er + ko + 4);
                float e[8] = {fa.x,fa.y,fa.z,fa.w, fb.x,fb.y,fb.z,fb.w};
                half8 hh, hl;
#pragma unroll
                for (int u = 0; u < 8; ++u) {
                    _Float16 hv = (_Float16)e[u];
                    hh[u] = hv;
                    hl[u] = (_Float16)((e[u] - (float)hv) * LOSC);
                }
                B_h[buf][bs] = hh; B_l[buf][bs] = hl;
            }
        } else {
            const _Float16 *sh, *sl; int kk;
            if (LAYER == 0)      { sh = xh0; sl = xl0; kk = ko - 128; }
            else if (kb < 16)    { sh = xh0; sl = xl0; kk = ko; }
            else                 { sh = xh1; sl = xl1; kk = ko - 512; }
#pragma unroll
            for (int bs = 0; bs < 4; ++bs) {
                const size_t ro = (size_t)(b0gl + bs * 16 + m) * H + kk;
                B_h[buf][bs] = *(const half8*)(sh + ro);
                B_l[buf][bs] = *(const half8*)(sl + ro);
            }
        }
    };

    ldkb(wq, 0);
#pragma unroll
    for (int i = 0; i < NKB; ++i) {
        const int cur = i & 1;
        if (i + 1 < NKB) ldkb(wq + 4 * (i + 1), cur ^ 1);   // prefetch next k-block
#pragma unroll
        for (int cs = 0; cs < 4; ++cs)
#pragma unroll
            for (int bs = 0; bs < 4; ++bs) {
                const int ti = cs * 4 + bs;
                acc0[ti] = __builtin_amdgcn_mfma_f32_16x16x32_f16(A_h[cur][cs], B_h[cur][bs], acc0[ti], 0, 0, 0);
                acc1[ti] = __builtin_amdgcn_mfma_f32_16x16x32_f16(A_h[cur][cs], B_l[cur][bs], acc1[ti], 0, 0, 0);
                acc1[ti] = __builtin_amdgcn_mfma_f32_16x16x32_f16(A_l[cur][cs], B_h[cur][bs], acc1[ti], 0, 0, 0);
            }
    }
}

// ---------------- persistent fused kernel: whole t-loop, 1 grid sync per step ------
// bid = ((layer*4 + bblk)*4 + chi)*8 + xcd, cblk = chi*8+xcd -> weights XCD-pinned
__global__ __launch_bounds__(256, 1) void k_lstm(
    const int* __restrict__ X, const float* __restrict__ emb,
    const float* __restrict__ b0, const float* __restrict__ b1,
    char* __restrict__ wsraw)
{
    extern __shared__ float red[];    // [4 waves][64 b][68]  (c-minor, +4 pad)

    const int tid = threadIdx.x, lane = tid & 63, wq = tid >> 6;
    const int m = lane & 15, qq = lane >> 4;
    const int bid = blockIdx.x;
    const int xcd = bid & 7, slot = bid >> 3;
    const int layer = slot >> 4, bblk = (slot >> 2) & 3, chi = slot & 3;
    const int cblk = chi * 8 + xcd;
    const int c0g = cblk * 64, b0gl = bblk * 64, j0g = cblk * 16;

    WS w = wsmap(wsraw);

    // ---- hoisted epilogue constants ----
    const int jj = lane & 15, bq = lane >> 4;
    const int j = j0g + jj;
    const float* bias = layer ? b1 : b0;
    const float bv0 = bias[0 * H + j], bv1 = bias[1 * H + j];
    const float bv2 = bias[2 * H + j], bv3 = bias[3 * H + j];

    // ---- register-resident recurrent state (unique owner per (bg, j)) ----
    float creg[4], hmreg[4];
    int lastr[4];
#pragma unroll
    for (int bi = 0; bi < 4; ++bi) {
        creg[bi]  = 0.f;
        hmreg[bi] = -FLT_MAX;
        lastr[bi] = w.last[b0gl + wq * 16 + bq + 4 * bi];
    }

    // Iteration t computes layer0(t) and layer1(t-1); one device-wide sync per step.
    for (int t = 0; t <= T; ++t) {
        const int tt = t - 1;
        const bool act = layer ? (t >= 1) : (t < T);
        if (act) {
            floatx4 acc0[16], acc1[16];
#pragma unroll
            for (int i = 0; i < 16; ++i) {
                floatx4 z = {0.f, 0.f, 0.f, 0.f};
                acc0[i] = z; acc1[i] = z;
            }

            if (layer == 0)
                run_mm<0>(t, X, emb, w.W0h, w.W0l,
                          w.h0h + (size_t)((t + 1) & 1) * NH, w.h0l + (size_t)((t + 1) & 1) * NH,
                          nullptr, nullptr, c0g, b0gl, m, qq, wq, acc0, acc1);
            else
                run_mm<1>(tt, X, emb, w.W1h, w.W1l,
                          w.h0h + (size_t)(tt & 1) * NH, w.h0l + (size_t)(tt & 1) * NH,
                          w.h1h + (size_t)((tt + 1) & 1) * NH, w.h1l + (size_t)((tt + 1) & 1) * NH,
                          c0g, b0gl, m, qq, wq, acc0, acc1);

            // ---- fold lo-acc, dump k-quarter partials ----
#pragma unroll
            for (int cs = 0; cs < 4; ++cs)
#pragma unroll
                for (int bs = 0; bs < 4; ++bs) {
                    floatx4 v = acc0[cs * 4 + bs] + acc1[cs * 4 + bs] * ILOSC;
                    const int bl = bs * 16 + m, cl = cs * 16 + qq * 4;
                    *(floatx4*)&red[((wq * 64 + bl) * 68 + cl)] = v;
                }
            __syncthreads();

            // ---- reduce 4 quarters + epilogue; wave wq owns b-strip [wq*16, wq*16+16) ----
            _Float16 *oh, *ol;
            if (layer == 0) { oh = w.h0h + (size_t)(t  & 1) * NH; ol = w.h0l + (size_t)(t  & 1) * NH; }
            else            { oh = w.h1h + (size_t)(tt & 1) * NH; ol = w.h1l + (size_t)(tt & 1) * NH; }

#pragma unroll
            for (int bi = 0; bi < 4; ++bi) {
                const int bl = wq * 16 + bq + 4 * bi;     // 16 lanes (jj) share this b
                const int bg = b0gl + bl;
                floatx4 g = *(floatx4*)&red[((0 * 64 + bl) * 68 + jj * 4)];
#pragma unroll
                for (int q2 = 1; q2 < 4; ++q2)
                    g += *(floatx4*)&red[((q2 * 64 + bl) * 68 + jj * 4)];
                float ig = fsig (g.x + bv0);
                float fg = fsig (g.y + bv1);
                float gg = ftanh(g.z + bv2);
                float og = fsig (g.w + bv3);
                float cn = fg * creg[bi] + ig * gg;
                float hn = og * ftanh(cn);
                creg[bi] = cn;
                _Float16 hh = (_Float16)hn;
                oh[(size_t)bg * H + j] = hh;
                ol[(size_t)bg * H + j] = (_Float16)((hn - (float)hh) * LOSC);
                if (layer == 1 && tt <= lastr[bi]) hmreg[bi] = fmaxf(hmreg[bi], hn);
            }
        }
        // red reuse next step is fenced by grid_sync's leading __syncthreads
        if (t < T) grid_sync(w.bar, (unsigned)(t + 1) * NBLK);
    }

    // ---- write out register-resident maxpool state ----
    if (layer == 1) {
#pragma unroll
        for (int bi = 0; bi < 4; ++bi) {
            const int bg = b0gl + wq * 16 + bq + 4 * bi;
            w.hmax[(size_t)bg * H + j] = hmreg[bi];
        }
    }
}

// ---------------- final: logits[b][cls] = sum_j hmax[b][j] * Wout[cls][j] + bout ----
__global__ __launch_bounds__(64) void k_out(const float* __restrict__ hmax,
                                            const float* __restrict__ Wout,
                                            const float* __restrict__ bout,
                                            float* __restrict__ out) {
    const int b = blockIdx.x * 64 + threadIdx.x;
    float a[NC] = {0.f, 0.f, 0.f, 0.f, 0.f};
    const float* hm = hmax + (size_t)b * H;
    for (int j = 0; j < H; ++j) {
        float hv = hm[j];
#pragma unroll
        for (int cls = 0; cls < NC; ++cls)
            a[cls] = fmaf(hv, Wout[cls * H + j], a[cls]);
    }
#pragma unroll
    for (int cls = 0; cls < NC; ++cls)
        out[b * NC + cls] = a[cls] + bout[cls];
}

// ---------------- launch ----------------
extern "C" void kernel_launch(void* const* d_in, const int* in_sizes, int n_in,
                              void* d_out, int out_size, void* d_ws, size_t ws_size,
                              hipStream_t stream) {
    const int*   X    = (const int*)  d_in[0];
    const float* emb  = (const float*)d_in[1];
    const float* Wih0 = (const float*)d_in[2];
    const float* Whh0 = (const float*)d_in[3];
    const float* b0   = (const float*)d_in[4];
    const float* Wih1 = (const float*)d_in[5];
    const float* Whh1 = (const float*)d_in[6];
    const float* b1   = (const float*)d_in[7];
    const float* Wout = (const float*)d_in[8];
    const float* bout = (const float*)d_in[9];
    float* out = (float*)d_out;
    char* ws = (char*)d_ws;
    WS w = wsmap(ws);

    k_prep<<<(NW0 + NW1 + 255) / 256, 256, 0, stream>>>(Wih0, Whh0, Wih1, Whh1, ws);
    k_init<<<2048, 256, 0, stream>>>(X, ws);

    // Whole recurrence in one persistent dispatch; 1 block/CU guaranteed co-resident.
    {
        const unsigned smem = (unsigned)(4 * 64 * 68 * sizeof(float));
        void* args[] = {(void*)&X, (void*)&emb, (void*)&b0, (void*)&b1, (void*)&ws};
        hipError_t e = hipLaunchCooperativeKernel((const void*)k_lstm, dim3(NBLK), dim3(256),
                                                  args, smem, stream);
        if (e != hipSuccess) {
            // 256 blocks on 256 CUs with nothing else resident: co-residency holds.
            k_lstm<<<NBLK, 256, smem, stream>>>(X, emb, b0, b1, ws);
        }
    }

    k_out<<<4, 64, 0, stream>>>(w.hmax, Wout, bout, out);
}

// Round 2
// 7711.499 us; speedup vs baseline: 1.2275x; 1.2275x over previous
//
#include <hip/hip_runtime.h>
#include <float.h>

#define V 50000
#define E 100
#define H 512
#define T 200
#define B 256
#define NC 5
#define K0 640            // layer0 concat-K: 128 (emb pad) + 512
#define K1 1024           // layer1 concat-K: 512 + 512
#define NH (B * H)        // 131072
#define NW0 (2048 * K0)
#define NW1 (2048 * K1)
#define LOSC 4096.0f      // lo-plane scale (2^12) keeps lo out of fp16 denormals
#define ILOSC (1.0f / 4096.0f)
#define NBLK 256          // persistent grid size (1 block / CU)

typedef _Float16 half8 __attribute__((ext_vector_type(8)));
typedef float floatx4 __attribute__((ext_vector_type(4)));
typedef unsigned long long u64;

// ---------------- activations ----------------
__device__ __forceinline__ float fsig(float x)  { return 1.f / (1.f + __expf(-x)); }
__device__ __forceinline__ float ftanh(float x) { return 1.f - 2.f / (__expf(2.f * x) + 1.f); }

// ---------------- coherence-point (L2-bypass) access helpers ----------------
// Agent-scope relaxed atomics compile to sc0/sc1 global ops: they miss L2 and
// complete at the device coherence point, so cross-XCD h traffic needs NO
// buffer_wbl2/buffer_inv — weights stay L2-resident across all 200 steps.
__device__ __forceinline__ half8 ld_h8_cc(const _Float16* p) {
    u64 a = __hip_atomic_load((const u64*)p,       __ATOMIC_RELAXED, __HIP_MEMORY_SCOPE_AGENT);
    u64 b = __hip_atomic_load(((const u64*)p) + 1, __ATOMIC_RELAXED, __HIP_MEMORY_SCOPE_AGENT);
    union { u64 u[2]; half8 h; } x; x.u[0] = a; x.u[1] = b; return x.h;
}
__device__ __forceinline__ void st_u64_cc(void* p, u64 v) {
    __hip_atomic_store((u64*)p, v, __ATOMIC_RELAXED, __HIP_MEMORY_SCOPE_AGENT);
}

// ---------------- workspace map ----------------
struct WS {
    _Float16 *W0h, *W0l, *W1h, *W1l;   // [2048][K] split planes, c = j*4+g
    _Float16 *h0h, *h0l, *h1h, *h1l;   // [2 slots][B][H] split planes (lo pre-scaled)
    float *c0, *c1, *hmax;             // c0/c1 unused (register-resident)
    int *last;
    unsigned *flags;                   // [NBLK] per-block monotonic step counters
};
__device__ __host__ inline WS wsmap(char* p) {
    WS w;
    w.W0h = (_Float16*)p;  p += (size_t)NW0 * 2;
    w.W0l = (_Float16*)p;  p += (size_t)NW0 * 2;
    w.W1h = (_Float16*)p;  p += (size_t)NW1 * 2;
    w.W1l = (_Float16*)p;  p += (size_t)NW1 * 2;
    w.h0h = (_Float16*)p;  p += (size_t)2 * NH * 2;
    w.h0l = (_Float16*)p;  p += (size_t)2 * NH * 2;
    w.h1h = (_Float16*)p;  p += (size_t)2 * NH * 2;
    w.h1l = (_Float16*)p;  p += (size_t)2 * NH * 2;
    w.c0   = (float*)p;    p += (size_t)NH * 4;
    w.c1   = (float*)p;    p += (size_t)NH * 4;
    w.hmax = (float*)p;    p += (size_t)NH * 4;
    w.last = (int*)p;      p += (size_t)B * 4;
    w.flags = (unsigned*)p;
    return w;
}

// ---------------- prep: split weights into fp16 hi/lo catenated layout ----------------
__global__ void k_prep(const float* __restrict__ Wih0, const float* __restrict__ Whh0,
                       const float* __restrict__ Wih1, const float* __restrict__ Whh1,
                       char* wsraw) {
    WS w = wsmap(wsraw);
    int idx = blockIdx.x * 256 + threadIdx.x;
    if (idx < NW0) {
        int c = idx / K0, k = idx - c * K0;
        int jx = c >> 2, g = c & 3, row = g * H + jx;
        float v = 0.f;
        if (k < 128) { if (k < E) v = Wih0[(size_t)row * E + k]; }
        else           v = Whh0[(size_t)row * H + (k - 128)];
        _Float16 hh = (_Float16)v;
        w.W0h[idx] = hh;
        w.W0l[idx] = (_Float16)((v - (float)hh) * LOSC);
    } else if (idx < NW0 + NW1) {
        int i2 = idx - NW0;
        int c = i2 / K1, k = i2 - c * K1;
        int jx = c >> 2, g = c & 3, row = g * H + jx;
        float v = (k < H) ? Wih1[(size_t)row * H + k]
                          : Whh1[(size_t)row * H + (k - H)];
        _Float16 hh = (_Float16)v;
        w.W1h[i2] = hh;
        w.W1l[i2] = (_Float16)((v - (float)hh) * LOSC);
    }
}

// ---------------- init: zero h planes, last[b], flags ----------------
__global__ void k_init(const int* __restrict__ X, char* wsraw) {
    WS w = wsmap(wsraw);
    int i = blockIdx.x * 256 + threadIdx.x;
    if (i < 524288) ((unsigned*)w.h0h)[i] = 0u;   // h0h,h0l,h1h,h1l contiguous = 2 MiB
    if (i < NBLK) w.flags[i] = 0u;
    if (i < B) {
        int l = -1;
        const int* xr = X + i * T;
        for (int t = 0; t < T; ++t) if (xr[t] != V) l = t;
        w.last[i] = l;
    }
}

// ---------------- grid barrier: flag array, no L2 flush ----------------
// Release: per-thread vmcnt drain (sc-stores are acked at the coherence point)
// + block barrier, then ONE relaxed agent store of this block's step counter.
// Acquire: wave 0 polls all 256 flags with relaxed agent loads (L2-bypassing),
// then a block barrier + compiler fence. No buffer_wbl2 / buffer_inv anywhere.
__device__ __forceinline__ void grid_barrier(unsigned* flags, unsigned tgt) {
    asm volatile("s_waitcnt vmcnt(0)" ::: "memory");
    __syncthreads();
    if (threadIdx.x == 0)
        __hip_atomic_store(&flags[blockIdx.x], tgt, __ATOMIC_RELAXED, __HIP_MEMORY_SCOPE_AGENT);
    if (threadIdx.x < 64) {
        const int l = threadIdx.x;
        for (;;) {
            unsigned f0 = __hip_atomic_load(&flags[l],       __ATOMIC_RELAXED, __HIP_MEMORY_SCOPE_AGENT);
            unsigned f1 = __hip_atomic_load(&flags[l + 64],  __ATOMIC_RELAXED, __HIP_MEMORY_SCOPE_AGENT);
            unsigned f2 = __hip_atomic_load(&flags[l + 128], __ATOMIC_RELAXED, __HIP_MEMORY_SCOPE_AGENT);
            unsigned f3 = __hip_atomic_load(&flags[l + 192], __ATOMIC_RELAXED, __HIP_MEMORY_SCOPE_AGENT);
            bool ok = (f0 >= tgt) & (f1 >= tgt) & (f2 >= tgt) & (f3 >= tgt);
            if (__all(ok)) break;
            __builtin_amdgcn_s_sleep(2);
        }
    }
    __syncthreads();
    asm volatile("" ::: "memory");   // keep subsequent loads below the spin
}

// ---------------- K-quarter MFMA loop (per wave) ----------------
// A (weights): plain cached loads — L2-resident. B (h planes): sc-atomic loads.
template <int LAYER>
__device__ __forceinline__ void run_mm(
    int t, const int* __restrict__ X, const float* __restrict__ emb,
    const _Float16* __restrict__ Wh, const _Float16* __restrict__ Wl,
    const _Float16* __restrict__ xh0, const _Float16* __restrict__ xl0,
    const _Float16* __restrict__ xh1, const _Float16* __restrict__ xl1,
    int c0g, int b0gl, int m, int qq, int wq,
    floatx4 (&acc0)[16], floatx4 (&acc1)[16])
{
    const int KT  = LAYER ? K1 : K0;
    const int NKB = LAYER ? 8 : 5;    // k-blocks of 32 per wave (kb = wq + 4*i)
    int erow[4];
    if (LAYER == 0) {
#pragma unroll
        for (int bs = 0; bs < 4; ++bs)
            erow[bs] = X[(b0gl + bs * 16 + m) * T + t];
    }
    half8 A_h[2][4], A_l[2][4], B_h[2][4], B_l[2][4];

    auto ldkb = [&](int kb, int buf) {
        const int ko = kb * 32 + qq * 8;
#pragma unroll
        for (int cs = 0; cs < 4; ++cs) {
            const size_t ro = (size_t)(c0g + cs * 16 + m) * KT + ko;
            A_h[buf][cs] = *(const half8*)(Wh + ro);
            A_l[buf][cs] = *(const half8*)(Wl + ro);
        }
        if (LAYER == 0 && kb < 4) {            // embedding part, convert on the fly
#pragma unroll
            for (int bs = 0; bs < 4; ++bs) {
                const float* er = emb + (size_t)erow[bs] * E;
                float4 fa = make_float4(0.f,0.f,0.f,0.f), fb = fa;
                if (ko <= 96) fa = *(const float4*)(er + ko);
                if (ko <= 92) fb = *(const float4*)(er + ko + 4);
                float e[8] = {fa.x,fa.y,fa.z,fa.w, fb.x,fb.y,fb.z,fb.w};
                half8 hh, hl;
#pragma unroll
                for (int u = 0; u < 8; ++u) {
                    _Float16 hv = (_Float16)e[u];
                    hh[u] = hv;
                    hl[u] = (_Float16)((e[u] - (float)hv) * LOSC);
                }
                B_h[buf][bs] = hh; B_l[buf][bs] = hl;
            }
        } else {
            const _Float16 *sh, *sl; int kk;
            if (LAYER == 0)      { sh = xh0; sl = xl0; kk = ko - 128; }
            else if (kb < 16)    { sh = xh0; sl = xl0; kk = ko; }
            else                 { sh = xh1; sl = xl1; kk = ko - 512; }
#pragma unroll
            for (int bs = 0; bs < 4; ++bs) {
                const size_t ro = (size_t)(b0gl + bs * 16 + m) * H + kk;
                B_h[buf][bs] = ld_h8_cc(sh + ro);
                B_l[buf][bs] = ld_h8_cc(sl + ro);
            }
        }
    };

    ldkb(wq, 0);
#pragma unroll
    for (int i = 0; i < NKB; ++i) {
        const int cur = i & 1;
        if (i + 1 < NKB) ldkb(wq + 4 * (i + 1), cur ^ 1);   // prefetch next k-block
#pragma unroll
        for (int cs = 0; cs < 4; ++cs)
#pragma unroll
            for (int bs = 0; bs < 4; ++bs) {
                const int ti = cs * 4 + bs;
                acc0[ti] = __builtin_amdgcn_mfma_f32_16x16x32_f16(A_h[cur][cs], B_h[cur][bs], acc0[ti], 0, 0, 0);
                acc1[ti] = __builtin_amdgcn_mfma_f32_16x16x32_f16(A_h[cur][cs], B_l[cur][bs], acc1[ti], 0, 0, 0);
                acc1[ti] = __builtin_amdgcn_mfma_f32_16x16x32_f16(A_l[cur][cs], B_h[cur][bs], acc1[ti], 0, 0, 0);
            }
    }
}

// ---------------- persistent fused kernel: whole t-loop, 1 flag barrier/step ------
// bid = ((layer*4 + bblk)*4 + chi)*8 + xcd, cblk = chi*8+xcd -> weights XCD-pinned
__global__ __launch_bounds__(256, 1) void k_lstm(
    const int* __restrict__ X, const float* __restrict__ emb,
    const float* __restrict__ b0, const float* __restrict__ b1,
    char* __restrict__ wsraw)
{
    extern __shared__ float red[];    // [4 waves][64 b][68]  (c-minor, +4 pad)

    const int tid = threadIdx.x, lane = tid & 63, wq = tid >> 6;
    const int m = lane & 15, qq = lane >> 4;
    const int bid = blockIdx.x;
    const int xcd = bid & 7, slot = bid >> 3;
    const int layer = slot >> 4, bblk = (slot >> 2) & 3, chi = slot & 3;
    const int cblk = chi * 8 + xcd;
    const int c0g = cblk * 64, b0gl = bblk * 64, j0g = cblk * 16;

    WS w = wsmap(wsraw);

    // ---- epilogue lane mapping: lane owns (1 b) x (4 contiguous j) ----
    const int b16 = lane & 15, jq = lane >> 4;
    const int bl_e = wq * 16 + b16;           // local b handled by this lane
    const int bg_e = b0gl + bl_e;
    const int jb = jq * 4;                    // local j quad base
    const float* bias = layer ? b1 : b0;
    float bv[4][4];
#pragma unroll
    for (int g = 0; g < 4; ++g)
#pragma unroll
        for (int u = 0; u < 4; ++u)
            bv[g][u] = bias[g * H + j0g + jb + u];

    // ---- register-resident recurrent state (unique owner per (bg, j)) ----
    float creg[4], hmreg[4];
#pragma unroll
    for (int u = 0; u < 4; ++u) { creg[u] = 0.f; hmreg[u] = -FLT_MAX; }
    const int lastb = w.last[bg_e];

    // Iteration t computes layer0(t) and layer1(t-1); one flag barrier per step.
    for (int t = 0; t <= T; ++t) {
        const int tt = t - 1;
        const bool act = layer ? (t >= 1) : (t < T);
        if (act) {
            floatx4 acc0[16], acc1[16];
#pragma unroll
            for (int i = 0; i < 16; ++i) {
                floatx4 z = {0.f, 0.f, 0.f, 0.f};
                acc0[i] = z; acc1[i] = z;
            }

            if (layer == 0)
                run_mm<0>(t, X, emb, w.W0h, w.W0l,
                          w.h0h + (size_t)((t + 1) & 1) * NH, w.h0l + (size_t)((t + 1) & 1) * NH,
                          nullptr, nullptr, c0g, b0gl, m, qq, wq, acc0, acc1);
            else
                run_mm<1>(tt, X, emb, w.W1h, w.W1l,
                          w.h0h + (size_t)(tt & 1) * NH, w.h0l + (size_t)(tt & 1) * NH,
                          w.h1h + (size_t)((tt + 1) & 1) * NH, w.h1l + (size_t)((tt + 1) & 1) * NH,
                          c0g, b0gl, m, qq, wq, acc0, acc1);

            // ---- fold lo-acc, dump k-quarter partials ----
#pragma unroll
            for (int cs = 0; cs < 4; ++cs)
#pragma unroll
                for (int bs = 0; bs < 4; ++bs) {
                    floatx4 v = acc0[cs * 4 + bs] + acc1[cs * 4 + bs] * ILOSC;
                    const int bl = bs * 16 + m, cl = cs * 16 + qq * 4;
                    *(floatx4*)&red[((wq * 64 + bl) * 68 + cl)] = v;
                }
            __syncthreads();

            // ---- reduce 4 quarters + epilogue ----
            _Float16 *oh, *ol;
            if (layer == 0) { oh = w.h0h + (size_t)(t  & 1) * NH; ol = w.h0l + (size_t)(t  & 1) * NH; }
            else            { oh = w.h1h + (size_t)(tt & 1) * NH; ol = w.h1l + (size_t)(tt & 1) * NH; }

            float hn4[4];
#pragma unroll
            for (int u = 0; u < 4; ++u) {
                floatx4 g = *(floatx4*)&red[((0 * 64 + bl_e) * 68 + (jb + u) * 4)];
#pragma unroll
                for (int q2 = 1; q2 < 4; ++q2)
                    g += *(floatx4*)&red[((q2 * 64 + bl_e) * 68 + (jb + u) * 4)];
                float ig = fsig (g.x + bv[0][u]);
                float fg = fsig (g.y + bv[1][u]);
                float gg = ftanh(g.z + bv[2][u]);
                float og = fsig (g.w + bv[3][u]);
                float cn = fg * creg[u] + ig * gg;
                float hn = og * ftanh(cn);
                creg[u] = cn;
                hn4[u] = hn;
            }
            if (layer == 1 && tt <= lastb) {
#pragma unroll
                for (int u = 0; u < 4; ++u) hmreg[u] = fmaxf(hmreg[u], hn4[u]);
            }
            union { _Float16 h[4]; u64 uu; } ph, pl;
#pragma unroll
            for (int u = 0; u < 4; ++u) {
                _Float16 hh = (_Float16)hn4[u];
                ph.h[u] = hh;
                pl.h[u] = (_Float16)((hn4[u] - (float)hh) * LOSC);
            }
            st_u64_cc(oh + (size_t)bg_e * H + j0g + jb, ph.uu);
            st_u64_cc(ol + (size_t)bg_e * H + j0g + jb, pl.uu);
        }
        // red reuse next step is fenced by the barrier's __syncthreads
        if (t < T) grid_barrier(w.flags, (unsigned)(t + 1));
    }

    // ---- write out register-resident maxpool state (plain stores; kernel-end
    //      L2 writeback makes them visible to k_out) ----
    if (layer == 1) {
        float4 hv = make_float4(hmreg[0], hmreg[1], hmreg[2], hmreg[3]);
        *(float4*)(w.hmax + (size_t)bg_e * H + j0g + jb) = hv;
    }
}

// ---------------- final: logits[b][cls] = sum_j hmax[b][j] * Wout[cls][j] + bout ----
__global__ __launch_bounds__(64) void k_out(const float* __restrict__ hmax,
                                            const float* __restrict__ Wout,
                                            const float* __restrict__ bout,
                                            float* __restrict__ out) {
    const int b = blockIdx.x * 64 + threadIdx.x;
    float a[NC] = {0.f, 0.f, 0.f, 0.f, 0.f};
    const float* hm = hmax + (size_t)b * H;
    for (int j = 0; j < H; ++j) {
        float hv = hm[j];
#pragma unroll
        for (int cls = 0; cls < NC; ++cls)
            a[cls] = fmaf(hv, Wout[cls * H + j], a[cls]);
    }
#pragma unroll
    for (int cls = 0; cls < NC; ++cls)
        out[b * NC + cls] = a[cls] + bout[cls];
}

// ---------------- launch ----------------
extern "C" void kernel_launch(void* const* d_in, const int* in_sizes, int n_in,
                              void* d_out, int out_size, void* d_ws, size_t ws_size,
                              hipStream_t stream) {
    const int*   X    = (const int*)  d_in[0];
    const float* emb  = (const float*)d_in[1];
    const float* Wih0 = (const float*)d_in[2];
    const float* Whh0 = (const float*)d_in[3];
    const float* b0   = (const float*)d_in[4];
    const float* Wih1 = (const float*)d_in[5];
    const float* Whh1 = (const float*)d_in[6];
    const float* b1   = (const float*)d_in[7];
    const float* Wout = (const float*)d_in[8];
    const float* bout = (const float*)d_in[9];
    float* out = (float*)d_out;
    char* ws = (char*)d_ws;
    WS w = wsmap(ws);

    k_prep<<<(NW0 + NW1 + 255) / 256, 256, 0, stream>>>(Wih0, Whh0, Wih1, Whh1, ws);
    k_init<<<2048, 256, 0, stream>>>(X, ws);

    // Whole recurrence in one persistent dispatch; 1 block/CU guaranteed co-resident.
    {
        const unsigned smem = (unsigned)(4 * 64 * 68 * sizeof(float));
        void* args[] = {(void*)&X, (void*)&emb, (void*)&b0, (void*)&b1, (void*)&ws};
        hipError_t e = hipLaunchCooperativeKernel((const void*)k_lstm, dim3(NBLK), dim3(256),
                                                  args, smem, stream);
        if (e != hipSuccess) {
            // 256 blocks on 256 CUs with nothing else resident: co-residency holds.
            k_lstm<<<NBLK, 256, smem, stream>>>(X, emb, b0, b1, ws);
        }
    }

    k_out<<<4, 64, 0, stream>>>(w.hmax, Wout, bout, out);
}

// Round 3
// 6565.327 us; speedup vs baseline: 1.4418x; 1.1746x over previous
//
#include <hip/hip_runtime.h>
#include <float.h>

#define V 50000
#define E 100
#define H 512
#define T 200
#define B 256
#define NC 5
#define K0 640            // layer0 concat-K: 128 (emb pad) + 512
#define K1 1024           // layer1 concat-K: 512 + 512
#define NH (B * H)        // 131072
#define NW0 (2048 * K0)
#define NW1 (2048 * K1)
#define LOSC 4096.0f      // lo-plane scale (2^12) keeps lo out of fp16 denormals
#define ILOSC (1.0f / 4096.0f)
#define NBLK 256          // persistent grid size (1 block / CU)
#define HSLOT (NH * 2)    // halves per h slot (hi+lo interleaved)

typedef _Float16 half8 __attribute__((ext_vector_type(8)));
typedef float floatx4 __attribute__((ext_vector_type(4)));
typedef unsigned long long u64;

// ---------------- activations ----------------
__device__ __forceinline__ float fsig(float x)  { return 1.f / (1.f + __expf(-x)); }
__device__ __forceinline__ float ftanh(float x) { return 1.f - 2.f / (__expf(2.f * x) + 1.f); }

// ---------------- coherence-point access helpers (agent-scope relaxed) ----------
__device__ __forceinline__ half8 ld_h8_cc(const _Float16* p) {
    u64 a = __hip_atomic_load((const u64*)p,       __ATOMIC_RELAXED, __HIP_MEMORY_SCOPE_AGENT);
    u64 b = __hip_atomic_load(((const u64*)p) + 1, __ATOMIC_RELAXED, __HIP_MEMORY_SCOPE_AGENT);
    union { u64 u[2]; half8 h; } x; x.u[0] = a; x.u[1] = b; return x.h;
}
__device__ __forceinline__ void st_u64_cc(void* p, u64 v) {
    __hip_atomic_store((u64*)p, v, __ATOMIC_RELAXED, __HIP_MEMORY_SCOPE_AGENT);
}

// ---------------- workspace map ----------------
// h layout (hi/lo interleaved): h[slot][b][H/8] records of 16 halves:
//   halves 0..7  = hi of j-chunk, halves 8..15 = lo of j-chunk.
// One 32B record per (b, 8j) -> B-frag hi+lo pair and epilogue store pair
// each touch a single cache line.
struct WS {
    _Float16 *W0h, *W0l, *W1h, *W1l;   // [2048][K] split planes, c = j*4+g
    _Float16 *h0, *h1;                 // [2 slots][B][H/8][16] interleaved
    float *c0, *c1, *hmax;             // c0/c1 unused (register-resident)
    int *last;
    unsigned *arr;                     // [NBLK] arrival words
    unsigned *gen;                     // generation word (own line)
};
__device__ __host__ inline WS wsmap(char* p) {
    WS w;
    w.W0h = (_Float16*)p;  p += (size_t)NW0 * 2;
    w.W0l = (_Float16*)p;  p += (size_t)NW0 * 2;
    w.W1h = (_Float16*)p;  p += (size_t)NW1 * 2;
    w.W1l = (_Float16*)p;  p += (size_t)NW1 * 2;
    w.h0  = (_Float16*)p;  p += (size_t)2 * HSLOT * 2;   // 1 MiB
    w.h1  = (_Float16*)p;  p += (size_t)2 * HSLOT * 2;   // 1 MiB
    w.c0   = (float*)p;    p += (size_t)NH * 4;
    w.c1   = (float*)p;    p += (size_t)NH * 4;
    w.hmax = (float*)p;    p += (size_t)NH * 4;
    w.last = (int*)p;      p += (size_t)B * 4;
    w.arr  = (unsigned*)p; p += (size_t)NBLK * 4;
    w.gen  = (unsigned*)p;
    return w;
}

// ---------------- prep: split weights into fp16 hi/lo catenated layout ----------------
__global__ void k_prep(const float* __restrict__ Wih0, const float* __restrict__ Whh0,
                       const float* __restrict__ Wih1, const float* __restrict__ Whh1,
                       char* wsraw) {
    WS w = wsmap(wsraw);
    int idx = blockIdx.x * 256 + threadIdx.x;
    if (idx < NW0) {
        int c = idx / K0, k = idx - c * K0;
        int jx = c >> 2, g = c & 3, row = g * H + jx;
        float v = 0.f;
        if (k < 128) { if (k < E) v = Wih0[(size_t)row * E + k]; }
        else           v = Whh0[(size_t)row * H + (k - 128)];
        _Float16 hh = (_Float16)v;
        w.W0h[idx] = hh;
        w.W0l[idx] = (_Float16)((v - (float)hh) * LOSC);
    } else if (idx < NW0 + NW1) {
        int i2 = idx - NW0;
        int c = i2 / K1, k = i2 - c * K1;
        int jx = c >> 2, g = c & 3, row = g * H + jx;
        float v = (k < H) ? Wih1[(size_t)row * H + k]
                          : Whh1[(size_t)row * H + (k - H)];
        _Float16 hh = (_Float16)v;
        w.W1h[i2] = hh;
        w.W1l[i2] = (_Float16)((v - (float)hh) * LOSC);
    }
}

// ---------------- init: zero h planes, last[b], barrier words ----------------
__global__ void k_init(const int* __restrict__ X, char* wsraw) {
    WS w = wsmap(wsraw);
    int i = blockIdx.x * 256 + threadIdx.x;
    if (i < 524288) ((unsigned*)w.h0)[i] = 0u;   // h0,h1 contiguous = 2 MiB
    if (i < NBLK) w.arr[i] = 0u;
    if (i == 0) *w.gen = 0u;
    if (i < B) {
        int l = -1;
        const int* xr = X + i * T;
        for (int t = 0; t < T; ++t) if (xr[t] != V) l = t;
        w.last[i] = l;
    }
}

// ---------------- prefetch of next step's h-independent fragments ----------------
// A (weights) always; B (emb via X) for layer 0.  Issued between barrier-arrive
// and barrier-wait so MALL latency hides under the wait.
template <int LAYER>
struct Pref { half8 Ah[4], Al[4], Bh[4], Bl[4]; };

template <int LAYER>
__device__ __forceinline__ void prefetch0(
    int t, const int* __restrict__ X, const float* __restrict__ emb,
    const _Float16* __restrict__ Wh, const _Float16* __restrict__ Wl,
    int c0g, int b0gl, int m, int qq, int wq, Pref<LAYER>& P)
{
    const int KT = LAYER ? K1 : K0;
    const int ko = wq * 32 + qq * 8;              // kb = wq
#pragma unroll
    for (int cs = 0; cs < 4; ++cs) {
        const size_t ro = (size_t)(c0g + cs * 16 + m) * KT + ko;
        P.Ah[cs] = *(const half8*)(Wh + ro);
        P.Al[cs] = *(const half8*)(Wl + ro);
    }
    if (LAYER == 0) {                             // kb = wq < 4 -> emb, convert now
#pragma unroll
        for (int bs = 0; bs < 4; ++bs) {
            int er = X[(b0gl + bs * 16 + m) * T + t];
            const float* p = emb + (size_t)er * E;
            float4 fa = make_float4(0.f,0.f,0.f,0.f), fb = fa;
            if (ko <= 96) fa = *(const float4*)(p + ko);
            if (ko <= 92) fb = *(const float4*)(p + ko + 4);
            float e[8] = {fa.x,fa.y,fa.z,fa.w, fb.x,fb.y,fb.z,fb.w};
#pragma unroll
            for (int u = 0; u < 8; ++u) {
                _Float16 hv = (_Float16)e[u];
                P.Bh[bs][u] = hv;
                P.Bl[bs][u] = (_Float16)((e[u] - (float)hv) * LOSC);
            }
        }
    }
}

// ---------------- K-quarter MFMA loop (per wave) ----------------
template <int LAYER>
__device__ __forceinline__ void run_mm(
    const Pref<LAYER>& P,
    const _Float16* __restrict__ Wh, const _Float16* __restrict__ Wl,
    const _Float16* __restrict__ x0, const _Float16* __restrict__ x1,
    int c0g, int b0gl, int m, int qq, int wq,
    floatx4 (&acc0)[16], floatx4 (&acc1)[16])
{
    const int KT  = LAYER ? K1 : K0;
    const int NKB = LAYER ? 8 : 5;    // k-blocks of 32 per wave (kb = wq + 4*i)
    half8 A_h[2][4], A_l[2][4], B_h[2][4], B_l[2][4];

    auto ldA = [&](int kb, int buf) {
        const int ko = kb * 32 + qq * 8;
#pragma unroll
        for (int cs = 0; cs < 4; ++cs) {
            const size_t ro = (size_t)(c0g + cs * 16 + m) * KT + ko;
            A_h[buf][cs] = *(const half8*)(Wh + ro);
            A_l[buf][cs] = *(const half8*)(Wl + ro);
        }
    };
    auto ldB = [&](int kb, int buf) {             // h-records only
        const int ko = kb * 32 + qq * 8;
        const _Float16* sx; int kk;
        if (LAYER == 0)   { sx = x0; kk = ko - 128; }
        else if (kb < 16) { sx = x0; kk = ko; }
        else              { sx = x1; kk = ko - 512; }
        const int ch = kk >> 3;
#pragma unroll
        for (int bs = 0; bs < 4; ++bs) {
            const _Float16* bp = sx + ((size_t)(b0gl + bs * 16 + m) * (H/8) + ch) * 16;
            B_h[buf][bs] = ld_h8_cc(bp);
            B_l[buf][bs] = ld_h8_cc(bp + 8);
        }
    };

    // buf0: A (and layer0 emb-B) from prefetch; layer1 B loaded now (needs fresh h)
#pragma unroll
    for (int cs = 0; cs < 4; ++cs) { A_h[0][cs] = P.Ah[cs]; A_l[0][cs] = P.Al[cs]; }
    if (LAYER == 0) {
#pragma unroll
        for (int bs = 0; bs < 4; ++bs) { B_h[0][bs] = P.Bh[bs]; B_l[0][bs] = P.Bl[bs]; }
    } else {
        ldB(wq, 0);
    }

#pragma unroll
    for (int i = 0; i < NKB; ++i) {
        const int cur = i & 1;
        if (i + 1 < NKB) { ldA(wq + 4 * (i + 1), cur ^ 1); ldB(wq + 4 * (i + 1), cur ^ 1); }
#pragma unroll
        for (int cs = 0; cs < 4; ++cs)
#pragma unroll
            for (int bs = 0; bs < 4; ++bs) {
                const int ti = cs * 4 + bs;
                acc0[ti] = __builtin_amdgcn_mfma_f32_16x16x32_f16(A_h[cur][cs], B_h[cur][bs], acc0[ti], 0, 0, 0);
                acc1[ti] = __builtin_amdgcn_mfma_f32_16x16x32_f16(A_h[cur][cs], B_l[cur][bs], acc1[ti], 0, 0, 0);
                acc1[ti] = __builtin_amdgcn_mfma_f32_16x16x32_f16(A_l[cur][cs], B_h[cur][bs], acc1[ti], 0, 0, 0);
            }
    }
}

// ---------------- persistent fused kernel ----------------
// bid = ((layer*4 + bblk)*4 + chi)*8 + xcd, cblk = chi*8+xcd -> weights XCD-pinned
__global__ __launch_bounds__(256, 1) void k_lstm(
    const int* __restrict__ X, const float* __restrict__ emb,
    const float* __restrict__ b0, const float* __restrict__ b1,
    char* __restrict__ wsraw)
{
    extern __shared__ float red[];    // [4 waves][64 b][68]  (c-minor, +4 pad)

    const int tid = threadIdx.x, lane = tid & 63, wq = tid >> 6;
    const int m = lane & 15, qq = lane >> 4;
    const int bid = blockIdx.x;
    const int xcd = bid & 7, slot = bid >> 3;
    const int layer = slot >> 4, bblk = (slot >> 2) & 3, chi = slot & 3;
    const int cblk = chi * 8 + xcd;
    const int c0g = cblk * 64, b0gl = bblk * 64, j0g = cblk * 16;

    WS w = wsmap(wsraw);

    // ---- epilogue lane mapping: lane owns (1 b) x (4 contiguous j) ----
    const int b16 = lane & 15, jq = lane >> 4;
    const int bl_e = wq * 16 + b16;
    const int bg_e = b0gl + bl_e;
    const int jb = jq * 4;
    const int ch_e  = (j0g + jb) >> 3;            // h record chunk
    const int hsel  = (jb >> 2) & 1;              // quad within chunk
    const float* bias = layer ? b1 : b0;
    float bv[4][4];
#pragma unroll
    for (int g = 0; g < 4; ++g)
#pragma unroll
        for (int u = 0; u < 4; ++u)
            bv[g][u] = bias[g * H + j0g + jb + u];

    float creg[4], hmreg[4];
#pragma unroll
    for (int u = 0; u < 4; ++u) { creg[u] = 0.f; hmreg[u] = -FLT_MAX; }
    const int lastb = w.last[bg_e];

    Pref<0> P0; Pref<1> P1;
    if (layer == 0) prefetch0<0>(0, X, emb, w.W0h, w.W0l, c0g, b0gl, m, qq, wq, P0);

    for (int t = 0; t <= T; ++t) {
        const int tt = t - 1;
        const bool act = layer ? (t >= 1) : (t < T);
        if (act) {
            floatx4 acc0[16], acc1[16];
#pragma unroll
            for (int i = 0; i < 16; ++i) {
                floatx4 z = {0.f, 0.f, 0.f, 0.f};
                acc0[i] = z; acc1[i] = z;
            }

            if (layer == 0)
                run_mm<0>(P0, w.W0h, w.W0l,
                          w.h0 + (size_t)((t + 1) & 1) * HSLOT, nullptr,
                          c0g, b0gl, m, qq, wq, acc0, acc1);
            else
                run_mm<1>(P1, w.W1h, w.W1l,
                          w.h0 + (size_t)(tt & 1) * HSLOT,
                          w.h1 + (size_t)((tt + 1) & 1) * HSLOT,
                          c0g, b0gl, m, qq, wq, acc0, acc1);

            // ---- fold lo-acc, dump k-quarter partials ----
#pragma unroll
            for (int cs = 0; cs < 4; ++cs)
#pragma unroll
                for (int bs = 0; bs < 4; ++bs) {
                    floatx4 v = acc0[cs * 4 + bs] + acc1[cs * 4 + bs] * ILOSC;
                    const int bl = bs * 16 + m, cl = cs * 16 + qq * 4;
                    *(floatx4*)&red[((wq * 64 + bl) * 68 + cl)] = v;
                }
            __syncthreads();

            // ---- reduce 4 quarters + epilogue ----
            _Float16* o = (layer ? w.h1 + (size_t)(tt & 1) * HSLOT
                                 : w.h0 + (size_t)(t  & 1) * HSLOT);
            float hn4[4];
#pragma unroll
            for (int u = 0; u < 4; ++u) {
                floatx4 g = *(floatx4*)&red[((0 * 64 + bl_e) * 68 + (jb + u) * 4)];
#pragma unroll
                for (int q2 = 1; q2 < 4; ++q2)
                    g += *(floatx4*)&red[((q2 * 64 + bl_e) * 68 + (jb + u) * 4)];
                float ig = fsig (g.x + bv[0][u]);
                float fg = fsig (g.y + bv[1][u]);
                float gg = ftanh(g.z + bv[2][u]);
                float og = fsig (g.w + bv[3][u]);
                float cn = fg * creg[u] + ig * gg;
                float hn = og * ftanh(cn);
                creg[u] = cn;
                hn4[u] = hn;
            }
            if (layer == 1 && tt <= lastb) {
#pragma unroll
                for (int u = 0; u < 4; ++u) hmreg[u] = fmaxf(hmreg[u], hn4[u]);
            }
            union { _Float16 h[4]; u64 uu; } ph, pl;
#pragma unroll
            for (int u = 0; u < 4; ++u) {
                _Float16 hh = (_Float16)hn4[u];
                ph.h[u] = hh;
                pl.h[u] = (_Float16)((hn4[u] - (float)hh) * LOSC);
            }
            _Float16* rec = o + ((size_t)bg_e * (H/8) + ch_e) * 16 + hsel * 4;
            st_u64_cc(rec,     ph.uu);            // hi quad
            st_u64_cc(rec + 8, pl.uu);            // lo quad (same 32B record/line)
        }

        if (t < T) {
            // ---- barrier arrive: drain h stores, publish arrival ----
            asm volatile("s_waitcnt vmcnt(0)" ::: "memory");
            __syncthreads();
            if (tid == 0)
                __hip_atomic_store(&w.arr[bid], (unsigned)(t + 1), __ATOMIC_RELAXED, __HIP_MEMORY_SCOPE_AGENT);

            // ---- barrier-overlapped prefetch for iteration t+1 ----
            const int nt = t + 1;
            if (layer == 0) { if (nt < T) prefetch0<0>(nt, X, emb, w.W0h, w.W0l, c0g, b0gl, m, qq, wq, P0); }
            else            prefetch0<1>(0, X, emb, w.W1h, w.W1l, c0g, b0gl, m, qq, wq, P1);

            // ---- barrier wait: block 0 aggregates, others poll one word ----
            const unsigned tgt = (unsigned)(t + 1);
            if (bid == 0) {
                if (tid < 64) {
                    for (;;) {
                        unsigned f0 = __hip_atomic_load(&w.arr[tid],       __ATOMIC_RELAXED, __HIP_MEMORY_SCOPE_AGENT);
                        unsigned f1 = __hip_atomic_load(&w.arr[tid + 64],  __ATOMIC_RELAXED, __HIP_MEMORY_SCOPE_AGENT);
                        unsigned f2 = __hip_atomic_load(&w.arr[tid + 128], __ATOMIC_RELAXED, __HIP_MEMORY_SCOPE_AGENT);
                        unsigned f3 = __hip_atomic_load(&w.arr[tid + 192], __ATOMIC_RELAXED, __HIP_MEMORY_SCOPE_AGENT);
                        bool ok = (f0 >= tgt) & (f1 >= tgt) & (f2 >= tgt) & (f3 >= tgt);
                        if (__all(ok)) break;
                        __builtin_amdgcn_s_sleep(2);
                    }
                    if (tid == 0)
                        __hip_atomic_store(w.gen, tgt, __ATOMIC_RELAXED, __HIP_MEMORY_SCOPE_AGENT);
                }
            } else {
                if (tid == 0) {
                    while (__hip_atomic_load(w.gen, __ATOMIC_RELAXED, __HIP_MEMORY_SCOPE_AGENT) < tgt)
                        __builtin_amdgcn_s_sleep(4);
                }
            }
            __syncthreads();
            asm volatile("" ::: "memory");
        }
    }

    // ---- write out register-resident maxpool state ----
    if (layer == 1) {
        float4 hv = make_float4(hmreg[0], hmreg[1], hmreg[2], hmreg[3]);
        *(float4*)(w.hmax + (size_t)bg_e * H + j0g + jb) = hv;
    }
}

// ---------------- final: logits ----------------
__global__ __launch_bounds__(64) void k_out(const float* __restrict__ hmax,
                                            const float* __restrict__ Wout,
                                            const float* __restrict__ bout,
                                            float* __restrict__ out) {
    const int b = blockIdx.x * 64 + threadIdx.x;
    float a[NC] = {0.f, 0.f, 0.f, 0.f, 0.f};
    const float* hm = hmax + (size_t)b * H;
    for (int j = 0; j < H; ++j) {
        float hv = hm[j];
#pragma unroll
        for (int cls = 0; cls < NC; ++cls)
            a[cls] = fmaf(hv, Wout[cls * H + j], a[cls]);
    }
#pragma unroll
    for (int cls = 0; cls < NC; ++cls)
        out[b * NC + cls] = a[cls] + bout[cls];
}

// ---------------- launch ----------------
extern "C" void kernel_launch(void* const* d_in, const int* in_sizes, int n_in,
                              void* d_out, int out_size, void* d_ws, size_t ws_size,
                              hipStream_t stream) {
    const int*   X    = (const int*)  d_in[0];
    const float* emb  = (const float*)d_in[1];
    const float* Wih0 = (const float*)d_in[2];
    const float* Whh0 = (const float*)d_in[3];
    const float* b0   = (const float*)d_in[4];
    const float* Wih1 = (const float*)d_in[5];
    const float* Whh1 = (const float*)d_in[6];
    const float* b1   = (const float*)d_in[7];
    const float* Wout = (const float*)d_in[8];
    const float* bout = (const float*)d_in[9];
    float* out = (float*)d_out;
    char* ws = (char*)d_ws;
    WS w = wsmap(ws);

    k_prep<<<(NW0 + NW1 + 255) / 256, 256, 0, stream>>>(Wih0, Whh0, Wih1, Whh1, ws);
    k_init<<<2048, 256, 0, stream>>>(X, ws);

    {
        const unsigned smem = (unsigned)(4 * 64 * 68 * sizeof(float));
        void* args[] = {(void*)&X, (void*)&emb, (void*)&b0, (void*)&b1, (void*)&ws};
        hipError_t e = hipLaunchCooperativeKernel((const void*)k_lstm, dim3(NBLK), dim3(256),
                                                  args, smem, stream);
        if (e != hipSuccess) {
            k_lstm<<<NBLK, 256, smem, stream>>>(X, emb, b0, b1, ws);
        }
    }

    k_out<<<4, 64, 0, stream>>>(w.hmax, Wout, bout, out);
}